// Round 11
// baseline (4654.505 us; speedup 1.0000x reference)
//
#include <hip/hip_runtime.h>

// ---------------------------------------------------------------------------
// AF(T)+LSTM fused pipeline for MI355X (gfx950).  B=8, T=2048, D=H=256.
// Input/output dtype (f32 vs bf16) detected AT RUNTIME from x's bit pattern;
// internal pipeline is bf16 with fp32 accumulation (LSTM U/h in f16).
// LSTM (round-11): r6 dot2 loop (96 reg / 32 LDS weight split, broadcast h)
// with gates-in-quad mapping (tid = col*4+g): gate exchange via 3 quad-shfl
// instead of the pre[] LDS round-trip, redundant per-quad nonlinearity, and
// a SINGLE barrier per step (double-buffered h makes it sufficient).
// ---------------------------------------------------------------------------

typedef unsigned short u16;
typedef unsigned int   u32;
typedef u16 u16x4 __attribute__((ext_vector_type(4)));
typedef u16 u16x8 __attribute__((ext_vector_type(8)));
typedef u32 u32x4 __attribute__((ext_vector_type(4)));
typedef short s16x8 __attribute__((ext_vector_type(8)));   // 8 bf16 (MFMA frag)
typedef float f32x4 __attribute__((ext_vector_type(4)));
typedef _Float16 f16x2 __attribute__((ext_vector_type(2)));

typedef __attribute__((address_space(3))) void* lds_vp;
typedef const __attribute__((address_space(1))) void* gbl_vp;
#define GLDS(gp, lp) __builtin_amdgcn_global_load_lds((gbl_vp)(gp), (lds_vp)(lp), 16, 0, 0)

__device__ __forceinline__ float b2f(u16 u){
  union { u32 i; float f; } c; c.i = ((u32)u) << 16; return c.f;
}
__device__ __forceinline__ u16 f2b(float f){           // RNE f32 -> bf16
  union { float f; u32 i; } c; c.f = f;
  u32 i = c.i;
  return (u16)((i + 0x7FFFu + ((i >> 16) & 1u)) >> 16);
}
__device__ __forceinline__ u16 f2h_bits(float f){
  _Float16 h = (_Float16)f;
  return __builtin_bit_cast(u16, h);
}
__device__ __forceinline__ float dot2(u32 a, u32 b, float acc){
#if __has_builtin(__builtin_amdgcn_fdot2)
  return __builtin_amdgcn_fdot2(__builtin_bit_cast(f16x2, a),
                                __builtin_bit_cast(f16x2, b), acc, false);
#else
  f16x2 x = __builtin_bit_cast(f16x2, a), y = __builtin_bit_cast(f16x2, b);
  return acc + (float)x[0]*(float)y[0] + (float)x[1]*(float)y[1];
#endif
}
__device__ __forceinline__ float sigm(float x){ return 1.f/(1.f + __expf(-x)); }
__device__ __forceinline__ float tanh_f(float x){
  float e = __expf(-2.f * fmaxf(x, -44.f));            // saturation-safe
  return (1.f - e)/(1.f + e);
}

// ---------------------------------------------------------------------------
// Runtime dtype detection: decode first 64 u16 of x as bf16.
// ---------------------------------------------------------------------------
__global__ void k_detect(const u16* __restrict__ x, int* __restrict__ flag){
  const int l = threadIdx.x;                  // 64 lanes
  const u16 u = x[l];
  const float v = b2f(u);
  const int bad = !(v == v) || fabsf(v) > 1e4f || (v != 0.f && fabsf(v) < 1e-30f);
  const int zev = ((l & 1) == 0) && (u == 0);
  unsigned long long mb = __ballot(bad);
  unsigned long long mz = __ballot(zev);
  if (l == 0) *flag = (mb != 0ull || __popcll(mz) >= 24) ? 1 : 0;
}

// x (f32 or bf16) -> xb bf16
__global__ __launch_bounds__(256) void k_cvt_x(const void* __restrict__ xin,
    u16* __restrict__ xb, const int* __restrict__ flag){
  const int isf = *flag;
  const size_t e = ((size_t)blockIdx.x*256 + threadIdx.x)*8;
  u16x8 o;
  if (isf){
    const float* p = (const float*)xin + e;
    f32x4 a = *(const f32x4*)p, b = *(const f32x4*)(p+4);
    o[0]=f2b(a[0]);o[1]=f2b(a[1]);o[2]=f2b(a[2]);o[3]=f2b(a[3]);
    o[4]=f2b(b[0]);o[5]=f2b(b[1]);o[6]=f2b(b[2]);o[7]=f2b(b[3]);
  } else {
    o = *(const u16x8*)((const u16*)xin + e);
  }
  *(u16x8*)(xb + e) = o;
}

// ---------------------------------------------------------------------------
// Generic 128x128-tile bf16 MFMA GEMM:  C = epi(A[M,K] @ Bt[N,K]^T + bias)
// EPI: 0 = +bias->bf16 ; 1 = sigmoid(+bias)->bf16 ; 2 = raw ->bf16 ;
//      3 = K-proj: e=exp(+bias), write [e*V | e] transposed into ekvT ;
//      4 = +bias->bf16, gate-interleaved store col' = (gc&255)*4 + (gc>>8).
// ---------------------------------------------------------------------------
template<int EPI>
__global__ __launch_bounds__(256)
void k_gemm(const u16* __restrict__ A, const u16* __restrict__ Bt,
            void* __restrict__ C, const u16* __restrict__ bias,
            const u16* __restrict__ aux,
            int M, int N, int K, int lda, int ldb, int ldc,
            long bsB /*elems*/, long bsC /*bytes*/)
{
  __shared__ __align__(16) u16 As[128*32];
  __shared__ __align__(16) u16 Bs[128*32];
  const int tid = threadIdx.x;
  const int wv = tid >> 6, l = tid & 63;
  const int m0 = blockIdx.x * 128, n0 = blockIdx.y * 128;
  const u16* Bp = Bt + (size_t)blockIdx.z * bsB;
  char* Cp = (char*)C + (size_t)blockIdx.z * bsC;

  const int rL = wv*16 + (l >> 2);      // staging row within tile
  const int cL = (l & 3) * 8;           // staging k-offset
  const u16* gA = A  + (size_t)(m0 + rL)*lda + cL;
  const u16* gB = Bp + (size_t)(n0 + rL)*ldb + cL;
  u16* lA = As + wv*512 + l*8;          // linear: dest == base + lane*16B
  u16* lB = Bs + wv*512 + l*8;

  f32x4 acc[4][4];
  #pragma unroll
  for (int m=0;m<4;++m)
    #pragma unroll
    for (int n=0;n<4;++n) acc[m][n] = f32x4{0.f,0.f,0.f,0.f};

  const int wr = wv >> 1, wc = wv & 1;
  const int lr = l & 15, lk = (l >> 4) * 8, lq = l >> 4;
  const int nk = K >> 5;
  for (int kt = 0; kt < nk; ++kt){
    __syncthreads();                    // previous compute done reading LDS
    GLDS(gA,                  lA);
    GLDS(gA + (size_t)64*lda, lA + 2048);
    GLDS(gB,                  lB);
    GLDS(gB + (size_t)64*ldb, lB + 2048);
    gA += 32; gB += 32;
    __syncthreads();                    // drains vmcnt -> tiles resident
    s16x8 af[4], bfr[4];
    #pragma unroll
    for (int m=0;m<4;++m) af[m]  = *(const s16x8*)&As[(wr*64 + m*16 + lr)*32 + lk];
    #pragma unroll
    for (int n=0;n<4;++n) bfr[n] = *(const s16x8*)&Bs[(wc*64 + n*16 + lr)*32 + lk];
    #pragma unroll
    for (int m=0;m<4;++m)
      #pragma unroll
      for (int n=0;n<4;++n)
        acc[m][n] = __builtin_amdgcn_mfma_f32_16x16x32_bf16(af[m], bfr[n], acc[m][n], 0, 0, 0);
  }

  // epilogue; C/D layout: col = lane&15, row = (lane>>4)*4 + reg  [m89]
  #pragma unroll
  for (int m=0;m<4;++m){
    const int gr0 = m0 + wr*64 + m*16 + lq*4;
    #pragma unroll
    for (int n=0;n<4;++n){
      const int gc = n0 + wc*64 + n*16 + lr;
      f32x4 v = acc[m][n];
      if constexpr (EPI == 0 || EPI == 1 || EPI == 4){
        const float bb = b2f(bias[gc]);
        u16* Cb = (u16*)Cp;
        const int cc = (EPI == 4) ? (((gc & 255) << 2) + (gc >> 8)) : gc;
        #pragma unroll
        for (int r=0;r<4;++r){
          float xv = v[r] + bb;
          if constexpr (EPI == 1) xv = sigm(xv);
          Cb[(size_t)(gr0 + r)*ldc + cc] = f2b(xv);
        }
      } else if constexpr (EPI == 2){
        u16* Cb = (u16*)Cp;
        #pragma unroll
        for (int r=0;r<4;++r) Cb[(size_t)(gr0 + r)*ldc + gc] = f2b(v[r]);
      } else {
        // EPI 3: rows are (z=gr0>>11, t=gr0&2047); write ekvT[z][gc][t]=e*V,
        // ekvT[z][gc+256][t]=e  (bf16, t-stride 1 -> 8B packed stores)
        const float bb = b2f(bias[gc]);
        u16x4 ekv, ek;
        #pragma unroll
        for (int r=0;r<4;++r){
          float e  = __expf(v[r] + bb);
          float vv = b2f(aux[(size_t)(gr0 + r)*256 + gc]);
          ek[r]  = f2b(e);
          ekv[r] = f2b(e * vv);
        }
        const int z = gr0 >> 11, t0 = gr0 & 2047;
        u16* base = (u16*)Cp + ((size_t)z*512 + gc)*2048 + t0;
        *(u16x4*)base = ekv;
        *(u16x4*)(base + (size_t)256*2048) = ek;
      }
    }
  }
}

// ---------------------------------------------------------------------------
// 256x256 transpose (13 jobs, dual-dtype read): weights -> Bt[N][K];
// mode=1 also converts to f16 (LSTM U matrices).
// ---------------------------------------------------------------------------
struct TJobs { const void* src[13]; u16* dst[13]; int mode[13]; };

__global__ __launch_bounds__(256) void k_transpose(TJobs jb, const int* __restrict__ flag){
  const int isf = *flag;
  const int mz = blockIdx.y;
  const void* in = jb.src[mz]; u16* out = jb.dst[mz]; const int mode = jb.mode[mz];
  const int bi = blockIdx.x >> 2, bj = blockIdx.x & 3;
  __shared__ float tile[64][65];
  const int tid = threadIdx.x;
  const int r = tid >> 3, c = (tid & 7) * 8;
  #pragma unroll
  for (int it=0; it<2; ++it){
    const size_t base = (size_t)(bi*64 + it*32 + r)*256 + bj*64 + c;
    float vals[8];
    if (isf){
      const float* p = (const float*)in + base;
      f32x4 a = *(const f32x4*)p, b = *(const f32x4*)(p+4);
      vals[0]=a[0];vals[1]=a[1];vals[2]=a[2];vals[3]=a[3];
      vals[4]=b[0];vals[5]=b[1];vals[6]=b[2];vals[7]=b[3];
    } else {
      u16x8 v = *(const u16x8*)((const u16*)in + base);
      #pragma unroll
      for (int u=0;u<8;++u) vals[u] = b2f(v[u]);
    }
    #pragma unroll
    for (int u=0;u<8;++u) tile[it*32 + r][c+u] = vals[u];
  }
  __syncthreads();
  #pragma unroll
  for (int it=0; it<2; ++it){
    const int rr = it*32 + r;           // output row (n)
    u16x8 o;
    #pragma unroll
    for (int u=0;u<8;++u){
      float xv = tile[c+u][rr];
      o[u] = mode ? f2h_bits(xv) : f2b(xv);
    }
    *(u16x8*)(out + (size_t)(bj*64 + rr)*256 + bi*64 + c) = o;
  }
}

// pack all 13 1-D params (5 gemm biases, 4 LN params, 4 gate biases) -> pp bf16
struct PJobs { const void* src[13]; };

__global__ __launch_bounds__(256) void k_pack_params(PJobs pj, u16* __restrict__ pp,
                                                     const int* __restrict__ flag){
  const int isf = *flag;
  const int t = threadIdx.x, bid = blockIdx.x;
  const void* s = pj.src[bid];
  const float v = isf ? ((const float*)s)[t] : b2f(((const u16*)s)[t]);
  pp[bid*256 + t] = f2b(v);
}

__global__ __launch_bounds__(256) void k_expw(const void* __restrict__ wb,
    u16* __restrict__ ew, const int* __restrict__ flag){
  const int isf = *flag;
  const size_t e = ((size_t)blockIdx.x*256 + threadIdx.x)*8;
  u16x8 o;
  if (isf){
    const float* p = (const float*)wb + e;
    f32x4 a = *(const f32x4*)p, b = *(const f32x4*)(p+4);
    o[0]=f2b(__expf(a[0]));o[1]=f2b(__expf(a[1]));o[2]=f2b(__expf(a[2]));o[3]=f2b(__expf(a[3]));
    o[4]=f2b(__expf(b[0]));o[5]=f2b(__expf(b[1]));o[6]=f2b(__expf(b[2]));o[7]=f2b(__expf(b[3]));
  } else {
    u16x8 v = *(const u16x8*)((const u16*)wb + e);
    #pragma unroll
    for (int u=0;u<8;++u) o[u] = f2b(__expf(b2f(v[u])));
  }
  *(u16x8*)(ew + e) = o;
}

// yt = sigmoid(Q) * num/den   (nd is bf16 [8][2048][512], num|den)
__global__ __launch_bounds__(256) void k_yt(const u16* __restrict__ sQ,
                                            const u16* __restrict__ nd,
                                            u16* __restrict__ yt){
  const int e = blockIdx.x*256 + threadIdx.x;     // one quad of elements
  const int m = e >> 6, n = (e & 63) << 2;
  const size_t ndb = ((size_t)(m >> 11)*2048 + (size_t)(m & 2047))*512 + n;
  u16x4 num = *(const u16x4*)(nd + ndb);
  u16x4 den = *(const u16x4*)(nd + ndb + 256);
  u16x4 q4  = *(const u16x4*)(sQ + (size_t)m*256 + n);
  u16x4 o;
  #pragma unroll
  for (int u=0;u<4;++u) o[u] = f2b(b2f(q4[u]) * b2f(num[u]) / b2f(den[u]));
  *(u16x4*)(yt + (size_t)m*256 + n) = o;
}

__device__ __forceinline__ float bsum(float v, float* red){
  #pragma unroll
  for (int o=1;o<64;o<<=1) v += __shfl_xor(v, o, 64);
  __syncthreads();                                  // protect red reuse
  if ((threadIdx.x & 63) == 0) red[threadIdx.x >> 6] = v;
  __syncthreads();
  return red[0]+red[1]+red[2]+red[3];
}

// prod = LN2( relu(att) * LN1(att) ), rowwise over H=256, one block per row
__global__ __launch_bounds__(256) void k_lnprod(const u16* __restrict__ att,
    const u16* __restrict__ pp, u16* __restrict__ prod){
  __shared__ float red[4];
  const int row = blockIdx.x, j = threadIdx.x;
  const u16* g1 = pp + 1280; const u16* b1 = pp + 1536;
  const u16* g2 = pp + 1792; const u16* b2_ = pp + 2048;
  const float a = b2f(att[(size_t)row*256 + j]);
  const float mu  = bsum(a, red) * (1.f/256.f);
  const float d   = a - mu;
  const float var = bsum(d*d, red) * (1.f/256.f);
  const float afx = d * rsqrtf(var + 1e-5f) * b2f(g1[j]) + b2f(b1[j]);
  const float y   = fmaxf(a, 0.f) * afx;
  const float mu2  = bsum(y, red) * (1.f/256.f);
  const float d2   = y - mu2;
  const float var2 = bsum(d2*d2, red) * (1.f/256.f);
  const float o = d2 * rsqrtf(var2 + 1e-5f) * b2f(g2[j]) + b2f(b2_[j]);
  prod[(size_t)row*256 + j] = f2b(o);
}

// ---------------------------------------------------------------------------
// LSTM scan (round 11).  8 blocks (1 CU/batch) x 1024 threads.
// Thread tid = col*4 + g: quad = one h-column, lanes = gates {i,f,c,o}.
// Dot2 loop identical to r6 (96 u32 reg-request -> 64 arch + 32 AGPR clean
// split; 32 u32 streamed from Wl4 LDS; h wave-uniform broadcast b128).
// Gate exchange: 3 quad shfl_xor + cndmask select (replaces pre[] LDS
// round-trip); nonlinearity redundant per quad; g==0 writes h + output.
// Double-buffered h => ONE barrier/step (r6 needed 2).
// P is gate-interleaved [b][t][col][i,f,c,o] bf16 (EPI=4 epilogue).
// ---------------------------------------------------------------------------
__global__ __launch_bounds__(1024)
void k_lstm7(const u16* __restrict__ P4, const u16* __restrict__ UT,
             void* __restrict__ outv, const int* __restrict__ flag)
{
  const int isf = *flag;
  const int b = blockIdx.x;
  const int tid = threadIdx.x;
  const int g = tid & 3, col = tid >> 2;
  const int gc = g*256 + col;                    // gate-column row in UT

  __shared__ u32x4 Wl4[8][1024];                 // 128KB: k-u32 [96,128)
  __shared__ __align__(16) u16 hl16[2][256];     // h double-buffer (f16)

  // ---- weights: UT is 4x [256][256] f16; row gc, full K
  const u32x4* wq = (const u32x4*)((const u32*)UT + (size_t)gc*128);
  u32x4 wr[24];                                  // 96 u32, static-indexed
  #pragma unroll
  for (int j=0;j<24;++j) wr[j] = wq[j];
  #pragma unroll
  for (int j=0;j<8;++j) Wl4[j][tid] = wq[24+j];
  #pragma unroll
  for (int j=0;j<24;++j)
    asm volatile("" : "+v"(wr[j].x), "+v"(wr[j].y), "+v"(wr[j].z), "+v"(wr[j].w));

  if (tid < 256){ hl16[0][tid] = 0; hl16[1][tid] = 0; }
  float c_state = 0.f, h_cur = 0.f;
  const u16* Pb = P4 + (size_t)b*2048*1024;
  u16 pn = Pb[tid];                              // EPI=4: [t][col][g] -> tid
  __syncthreads();

  int cur = 0;
  for (int t=0; t<2048; ++t){
    const float pcur = b2f(pn);
    if (t < 2047) pn = Pb[(size_t)(t+1)*1024 + tid];

    const u32x4* hb = (const u32x4*)&hl16[cur][0];   // 32 quads, wave-uniform
    float s0 = 0.f, s1 = 0.f;
    #pragma unroll
    for (int j=0;j<24;++j){                      // k-u32 [0,96) from regs
      const u32x4 h4 = hb[j];
      s0 = dot2(h4.x, wr[j].x, s0);
      s1 = dot2(h4.y, wr[j].y, s1);
      s0 = dot2(h4.z, wr[j].z, s0);
      s1 = dot2(h4.w, wr[j].w, s1);
    }
    #pragma unroll
    for (int j=0;j<8;++j){                       // k-u32 [96,128) from LDS
      const u32x4 h4 = hb[24+j];
      const u32x4 wt = Wl4[j][tid];
      s0 = dot2(h4.x, wt.x, s0);
      s1 = dot2(h4.y, wt.y, s1);
      s0 = dot2(h4.z, wt.z, s0);
      s1 = dot2(h4.w, wt.w, s1);
    }
    const float sp = s0 + s1 + pcur;             // my gate's pre-activation

    // quad exchange: lane g gets {sp=g, a=g^1, bq=g^2, cq=g^3}
    const float a  = __shfl_xor(sp, 1, 64);
    const float bq = __shfl_xor(sp, 2, 64);
    const float cq = __shfl_xor(a,  2, 64);
    const float p0 = (g==0)? sp : (g==1)? a : (g==2)? bq : cq;   // gate i
    const float p1 = (g==1)? sp : (g==0)? a : (g==3)? bq : cq;   // gate f
    const float p2 = (g==2)? sp : (g==3)? a : (g==0)? bq : cq;   // gate c~
    const float p3 = (g==3)? sp : (g==2)? a : (g==1)? bq : cq;   // gate o

    const float gi_ = sigm(p0);
    const float gf_ = sigm(p1);
    const float gg_ = tanh_f(p2);
    const float go_ = sigm(p3);
    c_state = gf_*c_state + gi_*gg_;             // redundant per quad
    h_cur = go_ * tanh_f(c_state);

    const int nxt = cur ^ 1;
    if (g == 0){
      hl16[nxt][col] = f2h_bits(h_cur);
      const size_t oe = (size_t)b*524288 + (size_t)t*256 + col;
      if (isf) ((float*)outv)[oe] = h_cur;
      else     ((u16*)outv)[oe]   = f2b(h_cur);
    }
    __syncthreads();                             // single barrier per step
    cur = nxt;
  }

  if (g == 0){
    const size_t o1 = 4194304 + (size_t)b*256 + col;
    if (isf){ ((float*)outv)[o1] = h_cur; ((float*)outv)[o1 + 2048] = c_state; }
    else    { ((u16*)outv)[o1] = f2b(h_cur); ((u16*)outv)[o1 + 2048] = f2b(c_state); }
  }
}

// ---------------------------------------------------------------------------
extern "C" void kernel_launch(void* const* d_in, const int* in_sizes, int n_in,
                              void* d_out, int out_size, void* d_ws, size_t ws_size,
                              hipStream_t stream)
{
  const void* x    = d_in[0];
  const void* fc_w = d_in[1];  const void* fc_b = d_in[2];
  const void* q_w  = d_in[3];  const void* q_b  = d_in[4];
  const void* k_w  = d_in[5];  const void* k_b  = d_in[6];
  const void* v_w  = d_in[7];  const void* v_b  = d_in[8];
  const void* p_w  = d_in[9];  const void* p_b  = d_in[10];
  const void* wbias= d_in[11];
  const void* n1g  = d_in[12]; const void* n1b  = d_in[13];
  const void* n2g  = d_in[14]; const void* n2b  = d_in[15];
  const void* w_i  = d_in[16]; const void* u_i  = d_in[17];
  const void* b_i  = d_in[18];
  const void* w_f  = d_in[19]; const void* u_f  = d_in[20];
  const void* b_f  = d_in[21];
  const void* w_c  = d_in[22]; const void* u_c  = d_in[23];
  const void* b_c  = d_in[24];
  const void* w_o  = d_in[25]; const void* u_o  = d_in[26];
  const void* b_o  = d_in[27];

  // workspace layout (68,819,968 bytes used)
  char* w = (char*)d_ws;
  u16* ew   = (u16*)(w + 0);              // exp(wbias)   8,388,608
  u16* WT   = (u16*)(w + 8388608);        // 9x Bt[256][256] bf16
  u16* UT   = (u16*)(w + 9568256);        // 4x UT f16 [256][256] (u_i..u_o)
  u16* pp   = (u16*)(w + 10092544);       // packed 1-D params (3328 u16)
  int* flag = (int*)(w + 10099200);
  u16* xf   = (u16*)(w + 10099712);       // A: 8,388,608
  u16* Vb   = (u16*)(w + 18488320);       // B: 8,388,608  (att later)
  u16* sQ   = (u16*)(w + 26876928);       // C: 8,388,608  (prod later)
  u16* ekvT = (u16*)(w + 35265536);       // D: 16,777,216 [8][512][2048] (xb early)
  u16* nd   = (u16*)(w + 52042752);       // E: 16,777,216 [8][2048][512] bf16
  // lifetime overlays:
  u16* xb   = ekvT;                       // x as bf16 (dead before ekvT written)
  u16* yt   = xf;                         // xf dead after K-proj
  u16* att  = Vb;                         // Vb dead after K-proj
  u16* prod = sQ;                         // sQ dead after yt
  u16* P    = ekvT;                       // D+E dead after yt; [8][2048][256][4] bf16

  // 0. dtype detection
  k_detect<<<1, 64, 0, stream>>>((const u16*)x, flag);

  // 1. input conversion / weight transposes (+ f16 convert for u_*)
  k_cvt_x<<<2048, 256, 0, stream>>>(x, xb, flag);
  TJobs jb;
  const void* srcs[13] = {fc_w, q_w, k_w, v_w, p_w, w_i, w_f, w_c, w_o, u_i, u_f, u_c, u_o};
  for (int i=0;i<13;++i){
    jb.src[i]  = srcs[i];
    jb.dst[i]  = (i < 9) ? (WT + (size_t)i*65536) : (UT + (size_t)(i-9)*65536);
    jb.mode[i] = (i < 9) ? 0 : 1;
  }
  k_transpose<<<dim3(16,13), 256, 0, stream>>>(jb, flag);
  PJobs pj;
  const void* psrc[13] = {fc_b, q_b, k_b, v_b, p_b, n1g, n1b, n2g, n2b, b_i, b_f, b_c, b_o};
  for (int i=0;i<13;++i) pj.src[i] = psrc[i];
  k_pack_params<<<13, 256, 0, stream>>>(pj, pp, flag);

  // 2. ew = exp(wbias)
  k_expw<<<2048, 256, 0, stream>>>(wbias, ew, flag);

  // 3-6. projections (biases from pp)
  k_gemm<0><<<dim3(128,2,1), 256, 0, stream>>>(xb, WT + 0*65536, xf, pp + 0, nullptr,
      16384,256,256, 256,256,256, 0,0);
  k_gemm<0><<<dim3(128,2,1), 256, 0, stream>>>(xf, WT + 3*65536, Vb, pp + 768, nullptr,
      16384,256,256, 256,256,256, 0,0);
  k_gemm<1><<<dim3(128,2,1), 256, 0, stream>>>(xf, WT + 1*65536, sQ, pp + 256, nullptr,
      16384,256,256, 256,256,256, 0,0);
  k_gemm<3><<<dim3(128,2,1), 256, 0, stream>>>(xf, WT + 2*65536, ekvT, pp + 512, Vb,
      16384,256,256, 256,256,2048, 0,0);

  // 7. AFT batched GEMM: nd[z] = ew @ [eKV|eK][z]   (bf16 out)
  k_gemm<2><<<dim3(16,4,8), 256, 0, stream>>>(ew, ekvT, nd, nullptr, nullptr,
      2048,512,2048, 2048,2048,512, (long)512*2048, (long)2048*512*2);

  // 8. yt = sigmoid(Q) * num/den
  k_yt<<<4096, 256, 0, stream>>>(sQ, nd, yt);

  // 9. att = yt @ p_w + p_b
  k_gemm<0><<<dim3(128,2,1), 256, 0, stream>>>(yt, WT + 4*65536, att, pp + 1024, nullptr,
      16384,256,256, 256,256,256, 0,0);

  // 10. prod = LN2( relu(att) * LN1(att) )
  k_lnprod<<<16384, 256, 0, stream>>>(att, pp, prod);

  // 11. P = prod @ [w_i|w_f|w_c|w_o] + gate biases, gate-interleaved (EPI=4)
  k_gemm<4><<<dim3(128,8,1), 256, 0, stream>>>(prod, WT + 5*65536, P, pp + 2304, nullptr,
      16384,1024,256, 256,256,1024, 0,0);

  // 12. LSTM scan (1 CU per batch) -> hidden_seq, h_t, c_t
  k_lstm7<<<8, 1024, 0, stream>>>(P, UT, d_out, flag);
}

// Round 12
// 3536.586 us; speedup vs baseline: 1.3161x; 1.3161x over previous
//
#include <hip/hip_runtime.h>

// ---------------------------------------------------------------------------
// AF(T)+LSTM fused pipeline for MI355X (gfx950).  B=8, T=2048, D=H=256.
// Input/output dtype (f32 vs bf16) detected AT RUNTIME from x's bit pattern;
// internal pipeline is bf16 with fp32 accumulation (LSTM U/h in f16).
// LSTM: 1 CU per batch, 1024 thr = 1 gate-col each; weights 96 u32 requested
// (allocator: 64 arch + 32 AGPR -- the clean split; >=112 scratch-spills,
// measured r8/r9) + 32 u32 streamed from LDS; h is wave-uniform broadcast.
// FINAL BUILD: round-6 structure (best measured 3539us, reproduced r10).
// Measured-out alternatives: cross-CU split (r5 +6us/step sync), k-quarter
// h-split (r7 dep-stalls), >=112-reg residency (r8/r9 scratch cliff),
// single-barrier quad exchange (r11 redundant-transcendental tax).
// ---------------------------------------------------------------------------

typedef unsigned short u16;
typedef unsigned int   u32;
typedef u16 u16x4 __attribute__((ext_vector_type(4)));
typedef u16 u16x8 __attribute__((ext_vector_type(8)));
typedef u32 u32x4 __attribute__((ext_vector_type(4)));
typedef short s16x8 __attribute__((ext_vector_type(8)));   // 8 bf16 (MFMA frag)
typedef float f32x4 __attribute__((ext_vector_type(4)));
typedef _Float16 f16x2 __attribute__((ext_vector_type(2)));

typedef __attribute__((address_space(3))) void* lds_vp;
typedef const __attribute__((address_space(1))) void* gbl_vp;
#define GLDS(gp, lp) __builtin_amdgcn_global_load_lds((gbl_vp)(gp), (lds_vp)(lp), 16, 0, 0)

__device__ __forceinline__ float b2f(u16 u){
  union { u32 i; float f; } c; c.i = ((u32)u) << 16; return c.f;
}
__device__ __forceinline__ u16 f2b(float f){           // RNE f32 -> bf16
  union { float f; u32 i; } c; c.f = f;
  u32 i = c.i;
  return (u16)((i + 0x7FFFu + ((i >> 16) & 1u)) >> 16);
}
__device__ __forceinline__ u16 f2h_bits(float f){
  _Float16 h = (_Float16)f;
  return __builtin_bit_cast(u16, h);
}
__device__ __forceinline__ float dot2(u32 a, u32 b, float acc){
#if __has_builtin(__builtin_amdgcn_fdot2)
  return __builtin_amdgcn_fdot2(__builtin_bit_cast(f16x2, a),
                                __builtin_bit_cast(f16x2, b), acc, false);
#else
  f16x2 x = __builtin_bit_cast(f16x2, a), y = __builtin_bit_cast(f16x2, b);
  return acc + (float)x[0]*(float)y[0] + (float)x[1]*(float)y[1];
#endif
}
__device__ __forceinline__ float sigm(float x){ return 1.f/(1.f + __expf(-x)); }
__device__ __forceinline__ float tanh_f(float x){
  float e = __expf(-2.f * fmaxf(x, -44.f));            // saturation-safe
  return (1.f - e)/(1.f + e);
}

// ---------------------------------------------------------------------------
// Runtime dtype detection: decode first 64 u16 of x as bf16.
// ---------------------------------------------------------------------------
__global__ void k_detect(const u16* __restrict__ x, int* __restrict__ flag){
  const int l = threadIdx.x;                  // 64 lanes
  const u16 u = x[l];
  const float v = b2f(u);
  const int bad = !(v == v) || fabsf(v) > 1e4f || (v != 0.f && fabsf(v) < 1e-30f);
  const int zev = ((l & 1) == 0) && (u == 0);
  unsigned long long mb = __ballot(bad);
  unsigned long long mz = __ballot(zev);
  if (l == 0) *flag = (mb != 0ull || __popcll(mz) >= 24) ? 1 : 0;
}

// x (f32 or bf16) -> xb bf16
__global__ __launch_bounds__(256) void k_cvt_x(const void* __restrict__ xin,
    u16* __restrict__ xb, const int* __restrict__ flag){
  const int isf = *flag;
  const size_t e = ((size_t)blockIdx.x*256 + threadIdx.x)*8;
  u16x8 o;
  if (isf){
    const float* p = (const float*)xin + e;
    f32x4 a = *(const f32x4*)p, b = *(const f32x4*)(p+4);
    o[0]=f2b(a[0]);o[1]=f2b(a[1]);o[2]=f2b(a[2]);o[3]=f2b(a[3]);
    o[4]=f2b(b[0]);o[5]=f2b(b[1]);o[6]=f2b(b[2]);o[7]=f2b(b[3]);
  } else {
    o = *(const u16x8*)((const u16*)xin + e);
  }
  *(u16x8*)(xb + e) = o;
}

// ---------------------------------------------------------------------------
// Generic 128x128-tile bf16 MFMA GEMM:  C = epi(A[M,K] @ Bt[N,K]^T + bias)
// EPI: 0 = +bias->bf16 ; 1 = sigmoid(+bias)->bf16 ; 2 = raw ->bf16 ;
//      3 = K-proj: e=exp(+bias), write [e*V | e] transposed into ekvT.
// ---------------------------------------------------------------------------
template<int EPI>
__global__ __launch_bounds__(256)
void k_gemm(const u16* __restrict__ A, const u16* __restrict__ Bt,
            void* __restrict__ C, const u16* __restrict__ bias,
            const u16* __restrict__ aux,
            int M, int N, int K, int lda, int ldb, int ldc,
            long bsB /*elems*/, long bsC /*bytes*/)
{
  __shared__ __align__(16) u16 As[128*32];
  __shared__ __align__(16) u16 Bs[128*32];
  const int tid = threadIdx.x;
  const int wv = tid >> 6, l = tid & 63;
  const int m0 = blockIdx.x * 128, n0 = blockIdx.y * 128;
  const u16* Bp = Bt + (size_t)blockIdx.z * bsB;
  char* Cp = (char*)C + (size_t)blockIdx.z * bsC;

  const int rL = wv*16 + (l >> 2);      // staging row within tile
  const int cL = (l & 3) * 8;           // staging k-offset
  const u16* gA = A  + (size_t)(m0 + rL)*lda + cL;
  const u16* gB = Bp + (size_t)(n0 + rL)*ldb + cL;
  u16* lA = As + wv*512 + l*8;          // linear: dest == base + lane*16B
  u16* lB = Bs + wv*512 + l*8;

  f32x4 acc[4][4];
  #pragma unroll
  for (int m=0;m<4;++m)
    #pragma unroll
    for (int n=0;n<4;++n) acc[m][n] = f32x4{0.f,0.f,0.f,0.f};

  const int wr = wv >> 1, wc = wv & 1;
  const int lr = l & 15, lk = (l >> 4) * 8, lq = l >> 4;
  const int nk = K >> 5;
  for (int kt = 0; kt < nk; ++kt){
    __syncthreads();                    // previous compute done reading LDS
    GLDS(gA,                  lA);
    GLDS(gA + (size_t)64*lda, lA + 2048);
    GLDS(gB,                  lB);
    GLDS(gB + (size_t)64*ldb, lB + 2048);
    gA += 32; gB += 32;
    __syncthreads();                    // drains vmcnt -> tiles resident
    s16x8 af[4], bfr[4];
    #pragma unroll
    for (int m=0;m<4;++m) af[m]  = *(const s16x8*)&As[(wr*64 + m*16 + lr)*32 + lk];
    #pragma unroll
    for (int n=0;n<4;++n) bfr[n] = *(const s16x8*)&Bs[(wc*64 + n*16 + lr)*32 + lk];
    #pragma unroll
    for (int m=0;m<4;++m)
      #pragma unroll
      for (int n=0;n<4;++n)
        acc[m][n] = __builtin_amdgcn_mfma_f32_16x16x32_bf16(af[m], bfr[n], acc[m][n], 0, 0, 0);
  }

  // epilogue; C/D layout: col = lane&15, row = (lane>>4)*4 + reg  [m89]
  #pragma unroll
  for (int m=0;m<4;++m){
    const int gr0 = m0 + wr*64 + m*16 + lq*4;
    #pragma unroll
    for (int n=0;n<4;++n){
      const int gc = n0 + wc*64 + n*16 + lr;
      f32x4 v = acc[m][n];
      if constexpr (EPI == 0 || EPI == 1){
        const float bb = b2f(bias[gc]);
        u16* Cb = (u16*)Cp;
        #pragma unroll
        for (int r=0;r<4;++r){
          float xv = v[r] + bb;
          if constexpr (EPI == 1) xv = sigm(xv);
          Cb[(size_t)(gr0 + r)*ldc + gc] = f2b(xv);
        }
      } else if constexpr (EPI == 2){
        u16* Cb = (u16*)Cp;
        #pragma unroll
        for (int r=0;r<4;++r) Cb[(size_t)(gr0 + r)*ldc + gc] = f2b(v[r]);
      } else {
        // EPI 3: rows are (z=gr0>>11, t=gr0&2047); write ekvT[z][gc][t]=e*V,
        // ekvT[z][gc+256][t]=e  (bf16, t-stride 1 -> 8B packed stores)
        const float bb = b2f(bias[gc]);
        u16x4 ekv, ek;
        #pragma unroll
        for (int r=0;r<4;++r){
          float e  = __expf(v[r] + bb);
          float vv = b2f(aux[(size_t)(gr0 + r)*256 + gc]);
          ek[r]  = f2b(e);
          ekv[r] = f2b(e * vv);
        }
        const int z = gr0 >> 11, t0 = gr0 & 2047;
        u16* base = (u16*)Cp + ((size_t)z*512 + gc)*2048 + t0;
        *(u16x4*)base = ekv;
        *(u16x4*)(base + (size_t)256*2048) = ek;
      }
    }
  }
}

// ---------------------------------------------------------------------------
// 256x256 transpose (13 jobs, dual-dtype read): weights -> Bt[N][K];
// mode=1 also converts to f16 (LSTM U matrices).
// ---------------------------------------------------------------------------
struct TJobs { const void* src[13]; u16* dst[13]; int mode[13]; };

__global__ __launch_bounds__(256) void k_transpose(TJobs jb, const int* __restrict__ flag){
  const int isf = *flag;
  const int mz = blockIdx.y;
  const void* in = jb.src[mz]; u16* out = jb.dst[mz]; const int mode = jb.mode[mz];
  const int bi = blockIdx.x >> 2, bj = blockIdx.x & 3;
  __shared__ float tile[64][65];
  const int tid = threadIdx.x;
  const int r = tid >> 3, c = (tid & 7) * 8;
  #pragma unroll
  for (int it=0; it<2; ++it){
    const size_t base = (size_t)(bi*64 + it*32 + r)*256 + bj*64 + c;
    float vals[8];
    if (isf){
      const float* p = (const float*)in + base;
      f32x4 a = *(const f32x4*)p, b = *(const f32x4*)(p+4);
      vals[0]=a[0];vals[1]=a[1];vals[2]=a[2];vals[3]=a[3];
      vals[4]=b[0];vals[5]=b[1];vals[6]=b[2];vals[7]=b[3];
    } else {
      u16x8 v = *(const u16x8*)((const u16*)in + base);
      #pragma unroll
      for (int u=0;u<8;++u) vals[u] = b2f(v[u]);
    }
    #pragma unroll
    for (int u=0;u<8;++u) tile[it*32 + r][c+u] = vals[u];
  }
  __syncthreads();
  #pragma unroll
  for (int it=0; it<2; ++it){
    const int rr = it*32 + r;           // output row (n)
    u16x8 o;
    #pragma unroll
    for (int u=0;u<8;++u){
      float xv = tile[c+u][rr];
      o[u] = mode ? f2h_bits(xv) : f2b(xv);
    }
    *(u16x8*)(out + (size_t)(bj*64 + rr)*256 + bi*64 + c) = o;
  }
}

// pack all 13 1-D params (5 gemm biases, 4 LN params, 4 gate biases) -> pp bf16
struct PJobs { const void* src[13]; };

__global__ __launch_bounds__(256) void k_pack_params(PJobs pj, u16* __restrict__ pp,
                                                     const int* __restrict__ flag){
  const int isf = *flag;
  const int t = threadIdx.x, bid = blockIdx.x;
  const void* s = pj.src[bid];
  const float v = isf ? ((const float*)s)[t] : b2f(((const u16*)s)[t]);
  pp[bid*256 + t] = f2b(v);
}

__global__ __launch_bounds__(256) void k_expw(const void* __restrict__ wb,
    u16* __restrict__ ew, const int* __restrict__ flag){
  const int isf = *flag;
  const size_t e = ((size_t)blockIdx.x*256 + threadIdx.x)*8;
  u16x8 o;
  if (isf){
    const float* p = (const float*)wb + e;
    f32x4 a = *(const f32x4*)p, b = *(const f32x4*)(p+4);
    o[0]=f2b(__expf(a[0]));o[1]=f2b(__expf(a[1]));o[2]=f2b(__expf(a[2]));o[3]=f2b(__expf(a[3]));
    o[4]=f2b(__expf(b[0]));o[5]=f2b(__expf(b[1]));o[6]=f2b(__expf(b[2]));o[7]=f2b(__expf(b[3]));
  } else {
    u16x8 v = *(const u16x8*)((const u16*)wb + e);
    #pragma unroll
    for (int u=0;u<8;++u) o[u] = f2b(__expf(b2f(v[u])));
  }
  *(u16x8*)(ew + e) = o;
}

// yt = sigmoid(Q) * num/den   (nd is bf16 [8][2048][512], num|den)
__global__ __launch_bounds__(256) void k_yt(const u16* __restrict__ sQ,
                                            const u16* __restrict__ nd,
                                            u16* __restrict__ yt){
  const int e = blockIdx.x*256 + threadIdx.x;     // one quad of elements
  const int m = e >> 6, n = (e & 63) << 2;
  const size_t ndb = ((size_t)(m >> 11)*2048 + (size_t)(m & 2047))*512 + n;
  u16x4 num = *(const u16x4*)(nd + ndb);
  u16x4 den = *(const u16x4*)(nd + ndb + 256);
  u16x4 q4  = *(const u16x4*)(sQ + (size_t)m*256 + n);
  u16x4 o;
  #pragma unroll
  for (int u=0;u<4;++u) o[u] = f2b(b2f(q4[u]) * b2f(num[u]) / b2f(den[u]));
  *(u16x4*)(yt + (size_t)m*256 + n) = o;
}

__device__ __forceinline__ float bsum(float v, float* red){
  #pragma unroll
  for (int o=1;o<64;o<<=1) v += __shfl_xor(v, o, 64);
  __syncthreads();                                  // protect red reuse
  if ((threadIdx.x & 63) == 0) red[threadIdx.x >> 6] = v;
  __syncthreads();
  return red[0]+red[1]+red[2]+red[3];
}

// prod = LN2( relu(att) * LN1(att) ), rowwise over H=256, one block per row
__global__ __launch_bounds__(256) void k_lnprod(const u16* __restrict__ att,
    const u16* __restrict__ pp, u16* __restrict__ prod){
  __shared__ float red[4];
  const int row = blockIdx.x, j = threadIdx.x;
  const u16* g1 = pp + 1280; const u16* b1 = pp + 1536;
  const u16* g2 = pp + 1792; const u16* b2_ = pp + 2048;
  const float a = b2f(att[(size_t)row*256 + j]);
  const float mu  = bsum(a, red) * (1.f/256.f);
  const float d   = a - mu;
  const float var = bsum(d*d, red) * (1.f/256.f);
  const float afx = d * rsqrtf(var + 1e-5f) * b2f(g1[j]) + b2f(b1[j]);
  const float y   = fmaxf(a, 0.f) * afx;
  const float mu2  = bsum(y, red) * (1.f/256.f);
  const float d2   = y - mu2;
  const float var2 = bsum(d2*d2, red) * (1.f/256.f);
  const float o = d2 * rsqrtf(var2 + 1e-5f) * b2f(g2[j]) + b2f(b2_[j]);
  prod[(size_t)row*256 + j] = f2b(o);
}

// ---------------------------------------------------------------------------
// LSTM scan.  8 blocks (1 CU per batch) x 1024 threads; thread = one gate-col
// (g = tid>>8 in {i,f,c,o}, col = tid&255), full K=256.
// Weights (f16 pairs): k-u32 [0,96) requested in regs (allocator grants
// 64 arch + 32 AGPR -- the only clean split, see r8/r9 cliff), k-u32
// [96,128) in LDS Wl4[8][1024] (lane-consecutive 16B, conflict-free).
// h: 256 f16 in LDS, wave-uniform broadcast ds_read_b128.  pre[1024] f32 in
// LDS; g==0 threads apply the gate nonlinearities.  2 barriers/step.
// P layout: [b][t][g*256+col] bf16 = plain EPI=0 GEMM output (ldc=1024).
// ---------------------------------------------------------------------------
__global__ __launch_bounds__(1024)
void k_lstm3(const u16* __restrict__ P, const u16* __restrict__ UT,
             void* __restrict__ outv, const int* __restrict__ flag)
{
  const int isf = *flag;
  const int b = blockIdx.x;
  const int tid = threadIdx.x;
  const int g = tid >> 8, col = tid & 255;

  __shared__ u32x4 Wl4[8][1024];                 // 128KB: k-u32 [96,128)
  __shared__ __align__(16) u16 hl16[2][256];     // h double-buffer (f16)
  __shared__ float pre[1024];

  // ---- weights: UT is 4x [256][256] f16, gate-col gc = tid -> row tid
  const u32x4* wq = (const u32x4*)((const u32*)UT + (size_t)tid*128);
  u32x4 wr[24];                                  // 96 VGPRs, static-indexed
  #pragma unroll
  for (int j=0;j<24;++j) wr[j] = wq[j];
  #pragma unroll
  for (int j=0;j<8;++j) Wl4[j][tid] = wq[24+j];
  #pragma unroll
  for (int j=0;j<24;++j)
    asm volatile("" : "+v"(wr[j].x), "+v"(wr[j].y), "+v"(wr[j].z), "+v"(wr[j].w));

  if (tid < 256){ hl16[0][tid] = 0; hl16[1][tid] = 0; }
  float c_state = 0.f, h_cur = 0.f;
  const u16* Pb = P + (size_t)b*2048*1024;
  u16 pn = Pb[tid];                              // t=0 prefetch
  __syncthreads();

  int cur = 0;
  for (int t=0; t<2048; ++t){
    const float pcur = b2f(pn);
    if (t < 2047) pn = Pb[(size_t)(t+1)*1024 + tid];

    const u32x4* hb = (const u32x4*)&hl16[cur][0];   // 32 quads, wave-uniform
    float s0 = 0.f, s1 = 0.f;
    #pragma unroll
    for (int j=0;j<24;++j){                      // k-u32 [0,96) from VGPR
      const u32x4 h4 = hb[j];
      s0 = dot2(h4.x, wr[j].x, s0);
      s1 = dot2(h4.y, wr[j].y, s1);
      s0 = dot2(h4.z, wr[j].z, s0);
      s1 = dot2(h4.w, wr[j].w, s1);
    }
    #pragma unroll
    for (int j=0;j<8;++j){                       // k-u32 [96,128) from LDS
      const u32x4 h4 = hb[24+j];
      const u32x4 wt = Wl4[j][tid];
      s0 = dot2(h4.x, wt.x, s0);
      s1 = dot2(h4.y, wt.y, s1);
      s0 = dot2(h4.z, wt.z, s0);
      s1 = dot2(h4.w, wt.w, s1);
    }
    pre[tid] = s0 + s1 + pcur;                   // includes W@x + bias (P)
    __syncthreads();                             // pre ready; hl[cur] reads done

    if (g == 0){
      const float gi_ = sigm(pre[col]);
      const float gf_ = sigm(pre[256 + col]);
      const float gg_ = tanh_f(pre[512 + col]);
      const float go_ = sigm(pre[768 + col]);
      c_state = gf_*c_state + gi_*gg_;
      h_cur = go_ * tanh_f(c_state);
      hl16[cur ^ 1][col] = f2h_bits(h_cur);
      const size_t oe = (size_t)b*524288 + (size_t)t*256 + col;
      if (isf) ((float*)outv)[oe] = h_cur;
      else     ((u16*)outv)[oe]   = f2b(h_cur);
    }
    __syncthreads();                             // new h visible
    cur ^= 1;
  }

  if (g == 0){
    const size_t o1 = 4194304 + (size_t)b*256 + col;
    if (isf){ ((float*)outv)[o1] = h_cur; ((float*)outv)[o1 + 2048] = c_state; }
    else    { ((u16*)outv)[o1] = f2b(h_cur); ((u16*)outv)[o1 + 2048] = f2b(c_state); }
  }
}

// ---------------------------------------------------------------------------
extern "C" void kernel_launch(void* const* d_in, const int* in_sizes, int n_in,
                              void* d_out, int out_size, void* d_ws, size_t ws_size,
                              hipStream_t stream)
{
  const void* x    = d_in[0];
  const void* fc_w = d_in[1];  const void* fc_b = d_in[2];
  const void* q_w  = d_in[3];  const void* q_b  = d_in[4];
  const void* k_w  = d_in[5];  const void* k_b  = d_in[6];
  const void* v_w  = d_in[7];  const void* v_b  = d_in[8];
  const void* p_w  = d_in[9];  const void* p_b  = d_in[10];
  const void* wbias= d_in[11];
  const void* n1g  = d_in[12]; const void* n1b  = d_in[13];
  const void* n2g  = d_in[14]; const void* n2b  = d_in[15];
  const void* w_i  = d_in[16]; const void* u_i  = d_in[17];
  const void* b_i  = d_in[18];
  const void* w_f  = d_in[19]; const void* u_f  = d_in[20];
  const void* b_f  = d_in[21];
  const void* w_c  = d_in[22]; const void* u_c  = d_in[23];
  const void* b_c  = d_in[24];
  const void* w_o  = d_in[25]; const void* u_o  = d_in[26];
  const void* b_o  = d_in[27];

  // workspace layout (68,819,968 bytes used)
  char* w = (char*)d_ws;
  u16* ew   = (u16*)(w + 0);              // exp(wbias)   8,388,608
  u16* WT   = (u16*)(w + 8388608);        // 9x Bt[256][256] bf16
  u16* UT   = (u16*)(w + 9568256);        // 4x UT f16 [256][256] (u_i..u_o)
  u16* pp   = (u16*)(w + 10092544);       // packed 1-D params (3328 u16)
  int* flag = (int*)(w + 10099200);
  u16* xf   = (u16*)(w + 10099712);       // A: 8,388,608
  u16* Vb   = (u16*)(w + 18488320);       // B: 8,388,608  (att later)
  u16* sQ   = (u16*)(w + 26876928);       // C: 8,388,608  (prod later)
  u16* ekvT = (u16*)(w + 35265536);       // D: 16,777,216 [8][512][2048] (xb early)
  u16* nd   = (u16*)(w + 52042752);       // E: 16,777,216 [8][2048][512] bf16
  // lifetime overlays:
  u16* xb   = ekvT;                       // x as bf16 (dead before ekvT written)
  u16* yt   = xf;                         // xf dead after K-proj
  u16* att  = Vb;                         // Vb dead after K-proj
  u16* prod = sQ;                         // sQ dead after yt
  u16* P    = ekvT;                       // D+E dead after yt; [8][2048][1024] bf16

  // 0. dtype detection
  k_detect<<<1, 64, 0, stream>>>((const u16*)x, flag);

  // 1. input conversion / weight transposes (+ f16 convert for u_*)
  k_cvt_x<<<2048, 256, 0, stream>>>(x, xb, flag);
  TJobs jb;
  const void* srcs[13] = {fc_w, q_w, k_w, v_w, p_w, w_i, w_f, w_c, w_o, u_i, u_f, u_c, u_o};
  for (int i=0;i<13;++i){
    jb.src[i]  = srcs[i];
    jb.dst[i]  = (i < 9) ? (WT + (size_t)i*65536) : (UT + (size_t)(i-9)*65536);
    jb.mode[i] = (i < 9) ? 0 : 1;
  }
  k_transpose<<<dim3(16,13), 256, 0, stream>>>(jb, flag);
  PJobs pj;
  const void* psrc[13] = {fc_b, q_b, k_b, v_b, p_b, n1g, n1b, n2g, n2b, b_i, b_f, b_c, b_o};
  for (int i=0;i<13;++i) pj.src[i] = psrc[i];
  k_pack_params<<<13, 256, 0, stream>>>(pj, pp, flag);

  // 2. ew = exp(wbias)
  k_expw<<<2048, 256, 0, stream>>>(wbias, ew, flag);

  // 3-6. projections (biases from pp)
  k_gemm<0><<<dim3(128,2,1), 256, 0, stream>>>(xb, WT + 0*65536, xf, pp + 0, nullptr,
      16384,256,256, 256,256,256, 0,0);
  k_gemm<0><<<dim3(128,2,1), 256, 0, stream>>>(xf, WT + 3*65536, Vb, pp + 768, nullptr,
      16384,256,256, 256,256,256, 0,0);
  k_gemm<1><<<dim3(128,2,1), 256, 0, stream>>>(xf, WT + 1*65536, sQ, pp + 256, nullptr,
      16384,256,256, 256,256,256, 0,0);
  k_gemm<3><<<dim3(128,2,1), 256, 0, stream>>>(xf, WT + 2*65536, ekvT, pp + 512, Vb,
      16384,256,256, 256,256,2048, 0,0);

  // 7. AFT batched GEMM: nd[z] = ew @ [eKV|eK][z]   (bf16 out)
  k_gemm<2><<<dim3(16,4,8), 256, 0, stream>>>(ew, ekvT, nd, nullptr, nullptr,
      2048,512,2048, 2048,2048,512, (long)512*2048, (long)2048*512*2);

  // 8. yt = sigmoid(Q) * num/den
  k_yt<<<4096, 256, 0, stream>>>(sQ, nd, yt);

  // 9. att = yt @ p_w + p_b
  k_gemm<0><<<dim3(128,2,1), 256, 0, stream>>>(yt, WT + 4*65536, att, pp + 1024, nullptr,
      16384,256,256, 256,256,256, 0,0);

  // 10. prod = LN2( relu(att) * LN1(att) )
  k_lnprod<<<16384, 256, 0, stream>>>(att, pp, prod);

  // 11. P = prod @ [w_i|w_f|w_c|w_o] + gate biases (plain layout, ldc=1024)
  k_gemm<0><<<dim3(128,8,1), 256, 0, stream>>>(prod, WT + 5*65536, P, pp + 2304, nullptr,
      16384,1024,256, 256,256,1024, 0,0);

  // 12. LSTM scan (1 CU per batch) -> hidden_seq, h_t, c_t
  k_lstm3<<<8, 1024, 0, stream>>>(P, UT, d_out, flag);
}